// Round 1
// baseline (179.977 us; speedup 1.0000x reference)
//
#include <hip/hip_runtime.h>
#include <hip/hip_bf16.h>

// Sizes are fixed by the problem.
#define NB 512     // birds
#define NC 512     // colors
#define HD 128     // hidden
#define NN 1024    // total nodes

// ---------------------------------------------------------------------------
// Per-row descending argsort of probs (exact lax.top_k semantics: descending
// value, ties -> lower index first). key = (~value_bits << 32) | index, sort
// ascending. probs in [0,1) so uint bits are monotone in value.
// ---------------------------------------------------------------------------
__global__ void k_sort(const float* __restrict__ probs, int* __restrict__ idx) {
  __shared__ unsigned long long keys[NC];
  const int row = blockIdx.x;
  const float* p = probs + row * NC;
  for (int t = threadIdx.x; t < NC; t += 256) {
    unsigned int bits = __float_as_uint(p[t]);
    keys[t] = ((unsigned long long)(~bits) << 32) | (unsigned int)t;
  }
  __syncthreads();
  for (int k = 2; k <= NC; k <<= 1) {
    for (int j = k >> 1; j > 0; j >>= 1) {
      for (int t = threadIdx.x; t < NC; t += 256) {
        int ixj = t ^ j;
        if (ixj > t) {
          bool up = ((t & k) == 0);
          unsigned long long a = keys[t], b = keys[ixj];
          if ((a > b) == up) { keys[t] = b; keys[ixj] = a; }
        }
      }
      __syncthreads();
    }
  }
  for (int t = threadIdx.x; t < NC; t += 256)
    idx[row * NC + t] = (int)(keys[t] & 0xFFFFFFFFu);
}

// ---------------------------------------------------------------------------
// bird_nodes = probs @ node_proj_w + b   (512x512 @ 512x128)
// 4 rows per block, 256 threads (128 cols x 2 row-slots).
// ---------------------------------------------------------------------------
__global__ void k_bird(const float* __restrict__ probs, const float* __restrict__ W,
                       const float* __restrict__ bias, float* __restrict__ x) {
  __shared__ float a[4][NC];
  const int r0 = blockIdx.x * 4;
  for (int t = threadIdx.x; t < 4 * NC; t += 256)
    a[t >> 9][t & 511] = probs[(r0 + (t >> 9)) * NC + (t & 511)];
  __syncthreads();
  const int n = threadIdx.x & 127, rr = threadIdx.x >> 7;
  for (int r = rr; r < 4; r += 2) {
    float acc = bias[n];
    for (int k = 0; k < NC; ++k)
      acc += a[r][k] * W[k * HD + n];
    x[(r0 + r) * HD + n] = acc;
  }
}

// color_nodes = node_proj_w + b  -> x rows 512..1023
__global__ void k_color(const float* __restrict__ W, const float* __restrict__ bias,
                        float* __restrict__ x) {
  int i = blockIdx.x * 256 + threadIdx.x;   // 0..65535
  x[NB * HD + i] = W[i] + bias[i & (HD - 1)];
}

// ---------------------------------------------------------------------------
// u_i = x[i] @ ew1[0:128,:] + eb1    (bird rows)
// v_j = x[512+j] @ ew1[128:256,:]    (color rows, bias folded into u only)
// ---------------------------------------------------------------------------
__global__ void k_uv(const float* __restrict__ x, const float* __restrict__ ew1,
                     const float* __restrict__ eb1, float* __restrict__ u,
                     float* __restrict__ v) {
  __shared__ float a[4][HD];
  const int r0 = blockIdx.x * 4;
  for (int t = threadIdx.x; t < 4 * HD; t += 256)
    a[t >> 7][t & 127] = x[(r0 + (t >> 7)) * HD + (t & 127)];
  __syncthreads();
  const int n = threadIdx.x & 127, rr = threadIdx.x >> 7;
  const bool isBird = (r0 < NB);
  const float* W = isBird ? ew1 : (ew1 + HD * HD);
  for (int r = rr; r < 4; r += 2) {
    float acc = isBird ? eb1[n] : 0.0f;
    for (int k = 0; k < HD; ++k)
      acc += a[r][k] * W[k * HD + n];
    const int row = r0 + r;
    if (isBird) u[row * HD + n] = acc;
    else        v[(row - NB) * HD + n] = acc;
  }
}

// ---------------------------------------------------------------------------
// R_i[h] = sum_j relu(u_i[h] + v_j[h]);  S_j[h] = sum_i relu(u_i[h] + v_j[h])
// blocks 0..127 -> R (4 i-rows each), 128..255 -> S (4 j-rows each).
// ---------------------------------------------------------------------------
__global__ void k_RS(const float* __restrict__ u, const float* __restrict__ v,
                     float* __restrict__ RS) {
  const int b = blockIdx.x;
  const int h = threadIdx.x & 127, rr = threadIdx.x >> 7;
  const float *mine, *other;
  int r0, outbase;
  if (b < 128) { mine = u; other = v; r0 = b * 4;        outbase = r0; }
  else         { mine = v; other = u; r0 = (b - 128) * 4; outbase = NB + r0; }
  const float base0 = mine[(r0 + rr) * HD + h];
  const float base1 = mine[(r0 + rr + 2) * HD + h];
  float acc0 = 0.f, acc1 = 0.f;
  for (int j = 0; j < 512; ++j) {
    float ov = other[j * HD + h];
    acc0 += fmaxf(base0 + ov, 0.f);
    acc1 += fmaxf(base1 + ov, 0.f);
  }
  RS[(outbase + rr) * HD + h]     = acc0;
  RS[(outbase + rr + 2) * HD + h] = acc1;
}

// aggr = RS @ ew2 + 512*eb2   (1024x128 @ 128x128)
__global__ void k_aggr(const float* __restrict__ RS, const float* __restrict__ ew2,
                       const float* __restrict__ eb2, float* __restrict__ aggr) {
  __shared__ float a[4][HD];
  const int r0 = blockIdx.x * 4;
  for (int t = threadIdx.x; t < 4 * HD; t += 256)
    a[t >> 7][t & 127] = RS[(r0 + (t >> 7)) * HD + (t & 127)];
  __syncthreads();
  const int n = threadIdx.x & 127, rr = threadIdx.x >> 7;
  for (int r = rr; r < 4; r += 2) {
    float acc = 512.0f * eb2[n];
    for (int k = 0; k < HD; ++k)
      acc += a[r][k] * ew2[k * HD + n];
    aggr[(r0 + r) * HD + n] = acc;
  }
}

// x_out = relu([x, aggr] @ nw1 + nb1) @ nw2 + nb2   (fused per 4-row tile)
__global__ void k_node(const float* __restrict__ x, const float* __restrict__ aggr,
                       const float* __restrict__ nw1, const float* __restrict__ nb1,
                       const float* __restrict__ nw2, const float* __restrict__ nb2,
                       float* __restrict__ xout) {
  __shared__ float a[4][2 * HD];
  __shared__ float h1[4][HD];
  const int r0 = blockIdx.x * 4;
  for (int t = threadIdx.x; t < 4 * HD; t += 256) {
    int r = t >> 7, c = t & 127;
    a[r][c]      = x[(r0 + r) * HD + c];
    a[r][HD + c] = aggr[(r0 + r) * HD + c];
  }
  __syncthreads();
  const int n = threadIdx.x & 127, rr = threadIdx.x >> 7;
  for (int r = rr; r < 4; r += 2) {
    float acc = nb1[n];
    for (int k = 0; k < 2 * HD; ++k)
      acc += a[r][k] * nw1[k * HD + n];
    h1[r][n] = fmaxf(acc, 0.0f);
  }
  __syncthreads();
  for (int r = rr; r < 4; r += 2) {
    float acc = nb2[n];
    for (int k = 0; k < HD; ++k)
      acc += h1[r][k] * nw2[k * HD + n];
    xout[(r0 + r) * HD + n] = acc;
  }
}

// gnn = x[:512] @ color_proj_w + b   (512x128 @ 128x512)
__global__ void k_gnn(const float* __restrict__ x, const float* __restrict__ W,
                      const float* __restrict__ bias, float* __restrict__ gnn) {
  __shared__ float a[4][HD];
  const int r0 = blockIdx.x * 4;
  for (int t = threadIdx.x; t < 4 * HD; t += 256)
    a[t >> 7][t & 127] = x[(r0 + (t >> 7)) * HD + (t & 127)];
  __syncthreads();
  const int n = threadIdx.x;   // 0..255
  for (int r = 0; r < 4; ++r) {
    float acc0 = bias[n], acc1 = bias[n + 256];
    for (int k = 0; k < HD; ++k) {
      float av = a[r][k];
      acc0 += av * W[k * NC + n];
      acc1 += av * W[k * NC + n + 256];
    }
    gnn[(r0 + r) * NC + n]       = acc0;
    gnn[(r0 + r) * NC + n + 256] = acc1;
  }
}

// cost[i][j] = 1 - gnn[i][idx[i][j]] * probs[i][idx[i][j]]
__global__ void k_final(const float* __restrict__ gnn, const float* __restrict__ probs,
                        const int* __restrict__ idx, float* __restrict__ out) {
  __shared__ float comb[NC];
  const int row = blockIdx.x;
  for (int t = threadIdx.x; t < NC; t += 256)
    comb[t] = gnn[row * NC + t] * probs[row * NC + t];
  __syncthreads();
  for (int t = threadIdx.x; t < NC; t += 256) {
    int c = idx[row * NC + t];
    out[row * NC + t] = 1.0f - comb[c];
  }
}

extern "C" void kernel_launch(void* const* d_in, const int* in_sizes, int n_in,
                              void* d_out, int out_size, void* d_ws, size_t ws_size,
                              hipStream_t stream) {
  const float* probs = (const float*)d_in[0];
  const float* npw   = (const float*)d_in[1];
  const float* npb   = (const float*)d_in[2];
  const float* ew1   = (const float*)d_in[3];
  const float* eb1   = (const float*)d_in[4];
  const float* ew2   = (const float*)d_in[5];
  const float* eb2   = (const float*)d_in[6];
  const float* nw1   = (const float*)d_in[7];
  const float* nb1   = (const float*)d_in[8];
  const float* nw2   = (const float*)d_in[9];
  const float* nb2   = (const float*)d_in[10];
  const float* cpw   = (const float*)d_in[11];
  const float* cpb   = (const float*)d_in[12];
  float* out = (float*)d_out;

  float* x0   = (float*)d_ws;            // 1024*128
  float* x1   = x0 + NN * HD;            // 1024*128
  float* u    = x1 + NN * HD;            // 512*128
  float* v    = u + NB * HD;             // 512*128
  float* RS   = v + NC * HD;             // 1024*128
  float* aggr = RS + NN * HD;            // 1024*128
  float* gnn  = aggr + NN * HD;          // 512*512
  int*   idx  = (int*)(gnn + NB * NC);   // 512*512 ints

  k_sort<<<512, 256, 0, stream>>>(probs, idx);
  k_bird<<<128, 256, 0, stream>>>(probs, npw, npb, x0);
  k_color<<<256, 256, 0, stream>>>(npw, npb, x0);

  float* xin = x0;
  float* xout = x1;
  for (int l = 0; l < 3; ++l) {
    k_uv  <<<256, 256, 0, stream>>>(xin, ew1 + l * 2 * HD * HD, eb1 + l * HD, u, v);
    k_RS  <<<256, 256, 0, stream>>>(u, v, RS);
    k_aggr<<<256, 256, 0, stream>>>(RS, ew2 + l * HD * HD, eb2 + l * HD, aggr);
    k_node<<<256, 256, 0, stream>>>(xin, aggr, nw1 + l * 2 * HD * HD, nb1 + l * HD,
                                    nw2 + l * HD * HD, nb2 + l * HD, xout);
    float* tmp = xin; xin = xout; xout = tmp;
  }

  k_gnn  <<<128, 256, 0, stream>>>(xin, cpw, cpb, gnn);
  k_final<<<512, 256, 0, stream>>>(gnn, probs, idx, out);
}